// Round 4
// baseline (552.136 us; speedup 1.0000x reference)
//
#include <hip/hip_runtime.h>
#include <hip/hip_fp16.h>

#define RAD 40
#define SEGF 16          // output rows per block-strip
#define TX 256           // output cols per tile (round-0 verified geometry)
#define HH 1024
#define WW 1024
// Round-3 post-mortem: TX=128 builds emitted ~10x WRITE (scratch spill
// signature, VGPR dropped to 40) — reverted to the verified TX=256 tiling.
// This version keeps the EXACT round-0 tile/traffic pattern but runs
// 2 waves per block, splitting the independent scan FIELDS across waves:
//   K_A: wave0 scans {I, p}, wave1 scans {I*p, I*I}
//   K_B: wave0 scans {a},    wave1 scans {b}
// -> 2x resident waves (6/SIMD vs 3), half the serial scan chain per wave,
//    identical global loads (duplicate issues hit L1) and identical stores.
// Epilogue is LDS-only (reads inclusive prefixes back from PF), split
// 128 cols per wave.

__device__ __forceinline__ float wscan64(float v, int lane) {
    #pragma unroll
    for (int d = 1; d < 64; d <<= 1) {
        float n = __shfl_up(v, d, 64);
        if (lane >= d) v += n;
    }
    return v;
}

// ---------------------------------------------------------------------------
// K_A: 2 waves per (channel, x-tile, y-strip). Vertical sliding sums of the
// wave's 2 fields in registers; per-row chained wave-scan over 2 chunks;
// epilogue reads all 4 fields' prefixes from LDS; writes a,b fp16x2.
// ---------------------------------------------------------------------------
__global__ __launch_bounds__(128, 6)
void fused_ab_kernel(const float* __restrict__ I, const float* __restrict__ p,
                     unsigned int* __restrict__ ab) {
    __shared__ __align__(16) float PF[4][512];
    const int tid = threadIdx.x;
    const int w = tid >> 6;          // wave id: 0 or 1
    const int l = tid & 63;
    const int bid = (int)blockIdx.x; // natural dispatch order (round-1 lesson)
    const int strip = bid & 63;
    const int xt = (bid >> 6) & 3;
    const int c = bid >> 8;
    const int x0 = xt * TX;
    const int y0 = strip * SEGF;
    const size_t plane = (size_t)c * (HH * WW);

    const int g1 = x0 - RAD + 4 * l;     // chunk0 col (mult of 4)
    const int g2 = g1 + 256;             // chunk1 col
    const bool v1 = (g1 >= 0) && (g1 < WW);
    const bool v2 = (l < 20) && (g2 >= 0) && (g2 < WW);

    // this wave's 2 vertical sliding sums [localfield][chunk][elem]
    // wave0: lf0 = sum I, lf1 = sum p ; wave1: lf0 = sum I*p, lf1 = sum I*I
    float s[2][2][4];
    #pragma unroll
    for (int f = 0; f < 2; ++f)
        #pragma unroll
        for (int ch = 0; ch < 2; ++ch)
            #pragma unroll
            for (int k = 0; k < 4; ++k) s[f][ch][k] = 0.f;

    auto load2 = [&](const float* src, int y, float* r) {
        const float* row = src + plane + (size_t)y * WW;
        float4 A = v1 ? *(const float4*)(row + g1) : make_float4(0.f,0.f,0.f,0.f);
        float4 B = v2 ? *(const float4*)(row + g2) : make_float4(0.f,0.f,0.f,0.f);
        r[0]=A.x; r[1]=A.y; r[2]=A.z; r[3]=A.w;
        r[4]=B.x; r[5]=B.y; r[6]=B.z; r[7]=B.w;
    };
    auto acc = [&](const float* ri, const float* rp, float sg) {
        #pragma unroll
        for (int j = 0; j < 8; ++j) {
            const int ch = j >> 2, k = j & 3;
            const float u0 = w ? ri[j] * rp[j] : ri[j];
            const float u1 = w ? ri[j] * ri[j] : rp[j];
            s[0][ch][k] += sg * u0;
            s[1][ch][k] += sg * u1;
        }
    };

    // prime rows [y0-RAD, y0+RAD), row at a time (unrolled prime implicated
    // in the TX=128 spill — keep it simple)
    int yp0 = y0 - RAD; if (yp0 < 0) yp0 = 0;
    int yp1 = y0 + RAD; if (yp1 > HH) yp1 = HH;
    for (int y = yp0; y < yp1; ++y) {
        float ri[8], rp[8];
        load2(I, y, ri); load2(p, y, rp);
        acc(ri, rp, 1.f);
    }

    float pi[8], pp[8];
    if (y0 + RAD < HH) { load2(I, y0 + RAD, pi); load2(p, y0 + RAD, pp); }

    for (int yy = y0; yy < y0 + SEGF; ++yy) {
        if (yy + RAD < HH) acc(pi, pp, 1.f);
        // prefetch next add-row and this row's sub-row
        float ni[8], np[8], si[8], sp[8];
        const int yn = yy + 1 + RAD;
        const bool nh = (yn < HH) && (yy + 1 < y0 + SEGF);
        if (nh) { load2(I, yn, ni); load2(p, yn, np); }
        const int ys = yy - RAD;
        if (ys >= 0) { load2(I, ys, si); load2(p, ys, sp); }

        // chained 2-chunk scans for this wave's two fields -> full-domain
        // inclusive prefixes into PF[f][0..511]
        #pragma unroll
        for (int fi = 0; fi < 2; ++fi) {
            const int f = (w << 1) | fi;
            float c0 = s[fi][0][0];
            float c1 = c0 + s[fi][0][1];
            float c2 = c1 + s[fi][0][2];
            float c3 = c2 + s[fi][0][3];
            float t = wscan64(c3, l);
            float tot0 = __shfl(t, 63);
            float b0 = t - c3;
            float d0 = s[fi][1][0];
            float d1 = d0 + s[fi][1][1];
            float d2 = d1 + s[fi][1][2];
            float d3 = d2 + s[fi][1][3];
            float u = wscan64(d3, l);
            float b1 = tot0 + (u - d3);
            ((float4*)PF[f])[l]      = make_float4(b0 + c0, b0 + c1, b0 + c2, b0 + c3);
            ((float4*)PF[f])[64 + l] = make_float4(b1 + d0, b1 + d1, b1 + d2, b1 + d3);
        }
        __syncthreads();

        int cv_hi = yy + RAD + 1; if (cv_hi > HH) cv_hi = HH;
        int cv_lo = yy - RAD;     if (cv_lo < 0)  cv_lo = 0;
        const float cntV = (float)(cv_hi - cv_lo);

        if (l < 32) {   // wave w handles quads q = w*32 .. w*32+31
            const int q = (w << 5) + l;
            // window sum for col-quad q, elem k:
            //   sum = incl[4q+k+80] - incl[4q+k-1]
            // incl[4q..4q+83] spanned by float4s {q-1(.w), q, q+20}
            float4 lo[4], cu[4], hi[4];
            #pragma unroll
            for (int f = 0; f < 4; ++f) {
                lo[f] = (q > 0) ? ((const float4*)PF[f])[q - 1]
                                : make_float4(0.f, 0.f, 0.f, 0.f);
                cu[f] = ((const float4*)PF[f])[q];
                hi[f] = ((const float4*)PF[f])[q + 20];
            }
            unsigned int outw[4];
            #pragma unroll
            for (int k = 0; k < 4; ++k) {
                const int go = x0 + 4 * q + k;
                const float eI  = (k == 0) ? lo[0].w : ((const float*)&cu[0])[k - 1];
                const float ep  = (k == 0) ? lo[1].w : ((const float*)&cu[1])[k - 1];
                const float eIp = (k == 0) ? lo[2].w : ((const float*)&cu[2])[k - 1];
                const float eII = (k == 0) ? lo[3].w : ((const float*)&cu[3])[k - 1];
                float bI  = ((const float*)&hi[0])[k] - eI;
                float bp  = ((const float*)&hi[1])[k] - ep;
                float bIp = ((const float*)&hi[2])[k] - eIp;
                float bII = ((const float*)&hi[3])[k] - eII;
                int hlo = go - RAD;     if (hlo < 0)  hlo = 0;
                int hhi = go + RAD + 1; if (hhi > WW) hhi = WW;
                const float ic = 1.f / (cntV * (float)(hhi - hlo));
                float mI = bI*ic, mp = bp*ic, mIp = bIp*ic, mII = bII*ic;
                float cov = mIp - mI * mp;
                float var = mII - mI * mI;
                float aa = cov / (var + 1e-3f);
                float bbv = mp - aa * mI;
                __half2 h = __float22half2_rn(make_float2(aa, bbv));
                outw[k] = *reinterpret_cast<unsigned int*>(&h);
            }
            ((uint4*)(ab + plane + (size_t)yy * WW))[(x0 >> 2) + q] =
                make_uint4(outw[0], outw[1], outw[2], outw[3]);
        }

        if (ys >= 0) acc(si, sp, -1.f);
        if (nh) {
            #pragma unroll
            for (int j = 0; j < 8; ++j) { pi[j] = ni[j]; pp[j] = np[j]; }
        }
        __syncthreads();   // protect next iter's PF writes vs this iter's reads
    }
}

// ---------------------------------------------------------------------------
// K_B: 2 waves per tile; wave0 scans a, wave1 scans b.
// Epilogue: out = mean_a * I + mean_b.
// ---------------------------------------------------------------------------
__global__ __launch_bounds__(128, 6)
void fused_out_kernel(const unsigned int* __restrict__ ab, const float* __restrict__ I,
                      float* __restrict__ out) {
    __shared__ __align__(16) float PF[2][512];
    const int tid = threadIdx.x;
    const int w = tid >> 6;
    const int l = tid & 63;
    const int bid = (int)blockIdx.x;
    const int strip = bid & 63;
    const int xt = (bid >> 6) & 3;
    const int c = bid >> 8;
    const int x0 = xt * TX;
    const int y0 = strip * SEGF;
    const size_t plane = (size_t)c * (HH * WW);
    const unsigned int* abp = ab + plane;

    const int g1 = x0 - RAD + 4 * l;
    const int g2 = g1 + 256;
    const bool v1 = (g1 >= 0) && (g1 < WW);
    const bool v2 = (l < 20) && (g2 >= 0) && (g2 < WW);

    float s[2][4];   // [chunk][elem] — this wave's single field
    #pragma unroll
    for (int ch = 0; ch < 2; ++ch)
        #pragma unroll
        for (int k = 0; k < 4; ++k) s[ch][k] = 0.f;

    // load this wave's half of the packed {a,b}: wave0 -> a (lo), wave1 -> b (hi)
    auto ld2 = [&](int y, float* r) {
        const unsigned int* row = abp + (size_t)y * WW;
        uint4 A = v1 ? *(const uint4*)(row + g1) : make_uint4(0u,0u,0u,0u);
        uint4 B = v2 ? *(const uint4*)(row + g2) : make_uint4(0u,0u,0u,0u);
        const unsigned int* aw = (const unsigned int*)&A;
        const unsigned int* bw = (const unsigned int*)&B;
        #pragma unroll
        for (int k = 0; k < 4; ++k) {
            float2 fa = __half22float2(*reinterpret_cast<const __half2*>(&aw[k]));
            float2 fb = __half22float2(*reinterpret_cast<const __half2*>(&bw[k]));
            r[k]     = w ? fa.y : fa.x;
            r[4 + k] = w ? fb.y : fb.x;
        }
    };
    auto acc1 = [&](const float* r, float sg) {
        #pragma unroll
        for (int j = 0; j < 8; ++j) s[j >> 2][j & 3] += sg * r[j];
    };

    int yp0 = y0 - RAD; if (yp0 < 0) yp0 = 0;
    int yp1 = y0 + RAD; if (yp1 > HH) yp1 = HH;
    for (int y = yp0; y < yp1; ++y) {
        float r[8];
        ld2(y, r);
        acc1(r, 1.f);
    }

    float pv[8];
    if (y0 + RAD < HH) ld2(y0 + RAD, pv);

    for (int yy = y0; yy < y0 + SEGF; ++yy) {
        if (yy + RAD < HH) acc1(pv, 1.f);
        float nv[8], sv[8];
        const int yn = yy + 1 + RAD;
        const bool nh = (yn < HH) && (yy + 1 < y0 + SEGF);
        if (nh) ld2(yn, nv);
        const int ys = yy - RAD;
        if (ys >= 0) ld2(ys, sv);

        {
            float c0 = s[0][0];
            float c1 = c0 + s[0][1];
            float c2 = c1 + s[0][2];
            float c3 = c2 + s[0][3];
            float t = wscan64(c3, l);
            float tot0 = __shfl(t, 63);
            float b0 = t - c3;
            float d0 = s[1][0];
            float d1 = d0 + s[1][1];
            float d2 = d1 + s[1][2];
            float d3 = d2 + s[1][3];
            float u = wscan64(d3, l);
            float b1 = tot0 + (u - d3);
            ((float4*)PF[w])[l]      = make_float4(b0 + c0, b0 + c1, b0 + c2, b0 + c3);
            ((float4*)PF[w])[64 + l] = make_float4(b1 + d0, b1 + d1, b1 + d2, b1 + d3);
        }
        __syncthreads();

        int cv_hi = yy + RAD + 1; if (cv_hi > HH) cv_hi = HH;
        int cv_lo = yy - RAD;     if (cv_lo < 0)  cv_lo = 0;
        const float cntV = (float)(cv_hi - cv_lo);

        if (l < 32) {
            const int q = (w << 5) + l;
            float4 lo[2], cu[2], hi[2];
            #pragma unroll
            for (int f = 0; f < 2; ++f) {
                lo[f] = (q > 0) ? ((const float4*)PF[f])[q - 1]
                                : make_float4(0.f, 0.f, 0.f, 0.f);
                cu[f] = ((const float4*)PF[f])[q];
                hi[f] = ((const float4*)PF[f])[q + 20];
            }
            float4 Iv = ((const float4*)(I + plane + (size_t)yy * WW))[(x0 >> 2) + q];
            const float* Ik = (const float*)&Iv;

            float oo[4];
            #pragma unroll
            for (int k = 0; k < 4; ++k) {
                const int go = x0 + 4 * q + k;
                const float ea = (k == 0) ? lo[0].w : ((const float*)&cu[0])[k - 1];
                const float eb = (k == 0) ? lo[1].w : ((const float*)&cu[1])[k - 1];
                float ba = ((const float*)&hi[0])[k] - ea;
                float bb = ((const float*)&hi[1])[k] - eb;
                int hlo = go - RAD;     if (hlo < 0)  hlo = 0;
                int hhi = go + RAD + 1; if (hhi > WW) hhi = WW;
                const float ic = 1.f / (cntV * (float)(hhi - hlo));
                oo[k] = (ba * ic) * Ik[k] + bb * ic;
            }
            ((float4*)(out + plane + (size_t)yy * WW))[(x0 >> 2) + q] =
                make_float4(oo[0], oo[1], oo[2], oo[3]);
        }

        if (ys >= 0) acc1(sv, -1.f);
        if (nh) {
            #pragma unroll
            for (int j = 0; j < 8; ++j) pv[j] = nv[j];
        }
        __syncthreads();
    }
}

extern "C" void kernel_launch(void* const* d_in, const int* in_sizes, int n_in,
                              void* d_out, int out_size, void* d_ws, size_t ws_size,
                              hipStream_t stream) {
    const float* I = (const float*)d_in[0];
    const float* p = (const float*)d_in[1];
    float* out = (float*)d_out;

    const int N = in_sizes[0];           // B*C*H*W
    const int BC = N / (HH * WW);

    unsigned int* ab = (unsigned int*)d_ws;   // fp16x2 {a,b} per pixel

    const int nblk = BC * (WW / TX) * (HH / SEGF);   // BC * 4 * 64
    fused_ab_kernel<<<dim3(nblk), 128, 0, stream>>>(I, p, ab);
    fused_out_kernel<<<dim3(nblk), 128, 0, stream>>>(ab, I, out);
}

// Round 5
// 357.328 us; speedup vs baseline: 1.5452x; 1.5452x over previous
//
#include <hip/hip_runtime.h>
#include <hip/hip_fp16.h>

#define RAD 40
#define SEGF 16          // output rows per block-strip
#define TX 256           // output cols per tile (round-0 verified geometry)
#define HH 1024
#define WW 1024
// Round-4 post-mortem: every build with __launch_bounds__(..., 6) allocated
// 40 VGPRs and spilled (~0.5-0.7 GB scratch WRITE traffic); the (.,3) build
// allocated 72 VGPRs and wrote the architectural 48 MB. min-waves=6 caps the
// allocator below this kernel's live set. ONLY change this round: (128,6) ->
// (128,3). Structure (field-split, verified correct in round 4) unchanged:
//   K_A: wave0 scans {I, p}, wave1 scans {I*p, I*I}
//   K_B: wave0 scans {a},    wave1 scans {b}
// -> 2x resident waves vs round 0, half the serial scan chain per wave,
//    identical global traffic (duplicate loads hit L1).

__device__ __forceinline__ float wscan64(float v, int lane) {
    #pragma unroll
    for (int d = 1; d < 64; d <<= 1) {
        float n = __shfl_up(v, d, 64);
        if (lane >= d) v += n;
    }
    return v;
}

// ---------------------------------------------------------------------------
// K_A: 2 waves per (channel, x-tile, y-strip). Vertical sliding sums of the
// wave's 2 fields in registers; per-row chained wave-scan over 2 chunks;
// epilogue reads all 4 fields' prefixes from LDS; writes a,b fp16x2.
// ---------------------------------------------------------------------------
__global__ __launch_bounds__(128, 3)
void fused_ab_kernel(const float* __restrict__ I, const float* __restrict__ p,
                     unsigned int* __restrict__ ab) {
    __shared__ __align__(16) float PF[4][512];
    const int tid = threadIdx.x;
    const int w = tid >> 6;          // wave id: 0 or 1
    const int l = tid & 63;
    const int bid = (int)blockIdx.x; // natural dispatch order (round-1 lesson)
    const int strip = bid & 63;
    const int xt = (bid >> 6) & 3;
    const int c = bid >> 8;
    const int x0 = xt * TX;
    const int y0 = strip * SEGF;
    const size_t plane = (size_t)c * (HH * WW);

    const int g1 = x0 - RAD + 4 * l;     // chunk0 col (mult of 4)
    const int g2 = g1 + 256;             // chunk1 col
    const bool v1 = (g1 >= 0) && (g1 < WW);
    const bool v2 = (l < 20) && (g2 >= 0) && (g2 < WW);

    // this wave's 2 vertical sliding sums [localfield][chunk][elem]
    // wave0: lf0 = sum I, lf1 = sum p ; wave1: lf0 = sum I*p, lf1 = sum I*I
    float s[2][2][4];
    #pragma unroll
    for (int f = 0; f < 2; ++f)
        #pragma unroll
        for (int ch = 0; ch < 2; ++ch)
            #pragma unroll
            for (int k = 0; k < 4; ++k) s[f][ch][k] = 0.f;

    auto load2 = [&](const float* src, int y, float* r) {
        const float* row = src + plane + (size_t)y * WW;
        float4 A = v1 ? *(const float4*)(row + g1) : make_float4(0.f,0.f,0.f,0.f);
        float4 B = v2 ? *(const float4*)(row + g2) : make_float4(0.f,0.f,0.f,0.f);
        r[0]=A.x; r[1]=A.y; r[2]=A.z; r[3]=A.w;
        r[4]=B.x; r[5]=B.y; r[6]=B.z; r[7]=B.w;
    };
    auto acc = [&](const float* ri, const float* rp, float sg) {
        #pragma unroll
        for (int j = 0; j < 8; ++j) {
            const int ch = j >> 2, k = j & 3;
            const float u0 = w ? ri[j] * rp[j] : ri[j];
            const float u1 = w ? ri[j] * ri[j] : rp[j];
            s[0][ch][k] += sg * u0;
            s[1][ch][k] += sg * u1;
        }
    };

    // prime rows [y0-RAD, y0+RAD), row at a time
    int yp0 = y0 - RAD; if (yp0 < 0) yp0 = 0;
    int yp1 = y0 + RAD; if (yp1 > HH) yp1 = HH;
    for (int y = yp0; y < yp1; ++y) {
        float ri[8], rp[8];
        load2(I, y, ri); load2(p, y, rp);
        acc(ri, rp, 1.f);
    }

    float pi[8], pp[8];
    if (y0 + RAD < HH) { load2(I, y0 + RAD, pi); load2(p, y0 + RAD, pp); }

    for (int yy = y0; yy < y0 + SEGF; ++yy) {
        if (yy + RAD < HH) acc(pi, pp, 1.f);
        // prefetch next add-row and this row's sub-row
        float ni[8], np[8], si[8], sp[8];
        const int yn = yy + 1 + RAD;
        const bool nh = (yn < HH) && (yy + 1 < y0 + SEGF);
        if (nh) { load2(I, yn, ni); load2(p, yn, np); }
        const int ys = yy - RAD;
        if (ys >= 0) { load2(I, ys, si); load2(p, ys, sp); }

        // chained 2-chunk scans for this wave's two fields -> full-domain
        // inclusive prefixes into PF[f][0..511]
        #pragma unroll
        for (int fi = 0; fi < 2; ++fi) {
            const int f = (w << 1) | fi;
            float c0 = s[fi][0][0];
            float c1 = c0 + s[fi][0][1];
            float c2 = c1 + s[fi][0][2];
            float c3 = c2 + s[fi][0][3];
            float t = wscan64(c3, l);
            float tot0 = __shfl(t, 63);
            float b0 = t - c3;
            float d0 = s[fi][1][0];
            float d1 = d0 + s[fi][1][1];
            float d2 = d1 + s[fi][1][2];
            float d3 = d2 + s[fi][1][3];
            float u = wscan64(d3, l);
            float b1 = tot0 + (u - d3);
            ((float4*)PF[f])[l]      = make_float4(b0 + c0, b0 + c1, b0 + c2, b0 + c3);
            ((float4*)PF[f])[64 + l] = make_float4(b1 + d0, b1 + d1, b1 + d2, b1 + d3);
        }
        __syncthreads();

        int cv_hi = yy + RAD + 1; if (cv_hi > HH) cv_hi = HH;
        int cv_lo = yy - RAD;     if (cv_lo < 0)  cv_lo = 0;
        const float cntV = (float)(cv_hi - cv_lo);

        if (l < 32) {   // wave w handles quads q = w*32 .. w*32+31
            const int q = (w << 5) + l;
            // window sum for col-quad q, elem k:
            //   sum = incl[4q+k+80] - incl[4q+k-1]
            // incl[4q..4q+83] spanned by float4s {q-1(.w), q, q+20}
            float4 lo[4], cu[4], hi[4];
            #pragma unroll
            for (int f = 0; f < 4; ++f) {
                lo[f] = (q > 0) ? ((const float4*)PF[f])[q - 1]
                                : make_float4(0.f, 0.f, 0.f, 0.f);
                cu[f] = ((const float4*)PF[f])[q];
                hi[f] = ((const float4*)PF[f])[q + 20];
            }
            unsigned int outw[4];
            #pragma unroll
            for (int k = 0; k < 4; ++k) {
                const int go = x0 + 4 * q + k;
                const float eI  = (k == 0) ? lo[0].w : ((const float*)&cu[0])[k - 1];
                const float ep  = (k == 0) ? lo[1].w : ((const float*)&cu[1])[k - 1];
                const float eIp = (k == 0) ? lo[2].w : ((const float*)&cu[2])[k - 1];
                const float eII = (k == 0) ? lo[3].w : ((const float*)&cu[3])[k - 1];
                float bI  = ((const float*)&hi[0])[k] - eI;
                float bp  = ((const float*)&hi[1])[k] - ep;
                float bIp = ((const float*)&hi[2])[k] - eIp;
                float bII = ((const float*)&hi[3])[k] - eII;
                int hlo = go - RAD;     if (hlo < 0)  hlo = 0;
                int hhi = go + RAD + 1; if (hhi > WW) hhi = WW;
                const float ic = 1.f / (cntV * (float)(hhi - hlo));
                float mI = bI*ic, mp = bp*ic, mIp = bIp*ic, mII = bII*ic;
                float cov = mIp - mI * mp;
                float var = mII - mI * mI;
                float aa = cov / (var + 1e-3f);
                float bbv = mp - aa * mI;
                __half2 h = __float22half2_rn(make_float2(aa, bbv));
                outw[k] = *reinterpret_cast<unsigned int*>(&h);
            }
            ((uint4*)(ab + plane + (size_t)yy * WW))[(x0 >> 2) + q] =
                make_uint4(outw[0], outw[1], outw[2], outw[3]);
        }

        if (ys >= 0) acc(si, sp, -1.f);
        if (nh) {
            #pragma unroll
            for (int j = 0; j < 8; ++j) { pi[j] = ni[j]; pp[j] = np[j]; }
        }
        __syncthreads();   // protect next iter's PF writes vs this iter's reads
    }
}

// ---------------------------------------------------------------------------
// K_B: 2 waves per tile; wave0 scans a, wave1 scans b.
// Epilogue: out = mean_a * I + mean_b.
// ---------------------------------------------------------------------------
__global__ __launch_bounds__(128, 3)
void fused_out_kernel(const unsigned int* __restrict__ ab, const float* __restrict__ I,
                      float* __restrict__ out) {
    __shared__ __align__(16) float PF[2][512];
    const int tid = threadIdx.x;
    const int w = tid >> 6;
    const int l = tid & 63;
    const int bid = (int)blockIdx.x;
    const int strip = bid & 63;
    const int xt = (bid >> 6) & 3;
    const int c = bid >> 8;
    const int x0 = xt * TX;
    const int y0 = strip * SEGF;
    const size_t plane = (size_t)c * (HH * WW);
    const unsigned int* abp = ab + plane;

    const int g1 = x0 - RAD + 4 * l;
    const int g2 = g1 + 256;
    const bool v1 = (g1 >= 0) && (g1 < WW);
    const bool v2 = (l < 20) && (g2 >= 0) && (g2 < WW);

    float s[2][4];   // [chunk][elem] — this wave's single field
    #pragma unroll
    for (int ch = 0; ch < 2; ++ch)
        #pragma unroll
        for (int k = 0; k < 4; ++k) s[ch][k] = 0.f;

    // load this wave's half of the packed {a,b}: wave0 -> a (lo), wave1 -> b (hi)
    auto ld2 = [&](int y, float* r) {
        const unsigned int* row = abp + (size_t)y * WW;
        uint4 A = v1 ? *(const uint4*)(row + g1) : make_uint4(0u,0u,0u,0u);
        uint4 B = v2 ? *(const uint4*)(row + g2) : make_uint4(0u,0u,0u,0u);
        const unsigned int* aw = (const unsigned int*)&A;
        const unsigned int* bw = (const unsigned int*)&B;
        #pragma unroll
        for (int k = 0; k < 4; ++k) {
            float2 fa = __half22float2(*reinterpret_cast<const __half2*>(&aw[k]));
            float2 fb = __half22float2(*reinterpret_cast<const __half2*>(&bw[k]));
            r[k]     = w ? fa.y : fa.x;
            r[4 + k] = w ? fb.y : fb.x;
        }
    };
    auto acc1 = [&](const float* r, float sg) {
        #pragma unroll
        for (int j = 0; j < 8; ++j) s[j >> 2][j & 3] += sg * r[j];
    };

    int yp0 = y0 - RAD; if (yp0 < 0) yp0 = 0;
    int yp1 = y0 + RAD; if (yp1 > HH) yp1 = HH;
    for (int y = yp0; y < yp1; ++y) {
        float r[8];
        ld2(y, r);
        acc1(r, 1.f);
    }

    float pv[8];
    if (y0 + RAD < HH) ld2(y0 + RAD, pv);

    for (int yy = y0; yy < y0 + SEGF; ++yy) {
        if (yy + RAD < HH) acc1(pv, 1.f);
        float nv[8], sv[8];
        const int yn = yy + 1 + RAD;
        const bool nh = (yn < HH) && (yy + 1 < y0 + SEGF);
        if (nh) ld2(yn, nv);
        const int ys = yy - RAD;
        if (ys >= 0) ld2(ys, sv);

        {
            float c0 = s[0][0];
            float c1 = c0 + s[0][1];
            float c2 = c1 + s[0][2];
            float c3 = c2 + s[0][3];
            float t = wscan64(c3, l);
            float tot0 = __shfl(t, 63);
            float b0 = t - c3;
            float d0 = s[1][0];
            float d1 = d0 + s[1][1];
            float d2 = d1 + s[1][2];
            float d3 = d2 + s[1][3];
            float u = wscan64(d3, l);
            float b1 = tot0 + (u - d3);
            ((float4*)PF[w])[l]      = make_float4(b0 + c0, b0 + c1, b0 + c2, b0 + c3);
            ((float4*)PF[w])[64 + l] = make_float4(b1 + d0, b1 + d1, b1 + d2, b1 + d3);
        }
        __syncthreads();

        int cv_hi = yy + RAD + 1; if (cv_hi > HH) cv_hi = HH;
        int cv_lo = yy - RAD;     if (cv_lo < 0)  cv_lo = 0;
        const float cntV = (float)(cv_hi - cv_lo);

        if (l < 32) {
            const int q = (w << 5) + l;
            float4 lo[2], cu[2], hi[2];
            #pragma unroll
            for (int f = 0; f < 2; ++f) {
                lo[f] = (q > 0) ? ((const float4*)PF[f])[q - 1]
                                : make_float4(0.f, 0.f, 0.f, 0.f);
                cu[f] = ((const float4*)PF[f])[q];
                hi[f] = ((const float4*)PF[f])[q + 20];
            }
            float4 Iv = ((const float4*)(I + plane + (size_t)yy * WW))[(x0 >> 2) + q];
            const float* Ik = (const float*)&Iv;

            float oo[4];
            #pragma unroll
            for (int k = 0; k < 4; ++k) {
                const int go = x0 + 4 * q + k;
                const float ea = (k == 0) ? lo[0].w : ((const float*)&cu[0])[k - 1];
                const float eb = (k == 0) ? lo[1].w : ((const float*)&cu[1])[k - 1];
                float ba = ((const float*)&hi[0])[k] - ea;
                float bb = ((const float*)&hi[1])[k] - eb;
                int hlo = go - RAD;     if (hlo < 0)  hlo = 0;
                int hhi = go + RAD + 1; if (hhi > WW) hhi = WW;
                const float ic = 1.f / (cntV * (float)(hhi - hlo));
                oo[k] = (ba * ic) * Ik[k] + bb * ic;
            }
            ((float4*)(out + plane + (size_t)yy * WW))[(x0 >> 2) + q] =
                make_float4(oo[0], oo[1], oo[2], oo[3]);
        }

        if (ys >= 0) acc1(sv, -1.f);
        if (nh) {
            #pragma unroll
            for (int j = 0; j < 8; ++j) pv[j] = nv[j];
        }
        __syncthreads();
    }
}

extern "C" void kernel_launch(void* const* d_in, const int* in_sizes, int n_in,
                              void* d_out, int out_size, void* d_ws, size_t ws_size,
                              hipStream_t stream) {
    const float* I = (const float*)d_in[0];
    const float* p = (const float*)d_in[1];
    float* out = (float*)d_out;

    const int N = in_sizes[0];           // B*C*H*W
    const int BC = N / (HH * WW);

    unsigned int* ab = (unsigned int*)d_ws;   // fp16x2 {a,b} per pixel

    const int nblk = BC * (WW / TX) * (HH / SEGF);   // BC * 4 * 64
    fused_ab_kernel<<<dim3(nblk), 128, 0, stream>>>(I, p, ab);
    fused_out_kernel<<<dim3(nblk), 128, 0, stream>>>(ab, I, out);
}

// Round 6
// 292.374 us; speedup vs baseline: 1.8885x; 1.2222x over previous
//
#include <hip/hip_runtime.h>
#include <hip/hip_fp16.h>

#define RAD 40
#define SEGF 16          // output rows per wave-strip
#define TX 256           // output cols per tile
#define HH 1024
#define WW 1024
// Round-0 geometry (verified best: 147+157 us). Round-6 change: wscan64 is
// now the classic GCN DPP wave64 inclusive scan (row_shr 1/2/4/8 +
// row_bcast15 rmask 0xa + row_bcast31 rmask 0xc): 6 dependent VALU ops
// (~25 cyc) instead of 6 dependent ds_bpermute (~240 cyc). Latency-bound
// kernel (VALU 34%, DS ~25%, HBM 33% — nothing saturated at 3 waves/SIMD),
// so the serial scan chain is the target. Traffic/tiling untouched.
// History: (.,6) launch bounds caused VGPR=40 spill storms (rounds 1-4);
// field-split across 2 waves doubled instruction issue for no win (round 5).

template<int CTRL, int RMASK>
__device__ __forceinline__ float dpp_add(float v) {
    // v += dpp_shifted(v); invalid/masked-out lanes contribute old=0.
    int t = __builtin_amdgcn_update_dpp(0, __float_as_int(v), CTRL, RMASK, 0xf, false);
    return v + __int_as_float(t);
}

__device__ __forceinline__ float wscan64(float v, int) {
    v = dpp_add<0x111, 0xf>(v);   // row_shr:1  — intra-16 scan
    v = dpp_add<0x112, 0xf>(v);   // row_shr:2
    v = dpp_add<0x114, 0xf>(v);   // row_shr:4
    v = dpp_add<0x118, 0xf>(v);   // row_shr:8
    v = dpp_add<0x142, 0xa>(v);   // row_bcast:15 -> rows 1,3
    v = dpp_add<0x143, 0xc>(v);   // row_bcast:31 -> rows 2,3
    return v;
}

// ---------------------------------------------------------------------------
// K_A: one wave per (channel, x-tile, y-strip). Vertical sliding sums of
// I, p, I*p, I*I in registers; per-row chained wave-scan; writes a,b fp16x2.
// ---------------------------------------------------------------------------
__global__ __launch_bounds__(64, 3)
void fused_ab_kernel(const float* __restrict__ I, const float* __restrict__ p,
                     unsigned int* __restrict__ ab) {
    __shared__ __align__(16) float PF[4][512];
    const int l = threadIdx.x;
    const int bid = blockIdx.x;
    const int strip = bid & 63;
    const int xt = (bid >> 6) & 3;
    const int c = bid >> 8;
    const int x0 = xt * TX;
    const int y0 = strip * SEGF;
    const size_t plane = (size_t)c * (HH * WW);

    const int g1 = x0 - RAD + 4 * l;     // chunk0 col (mult of 4)
    const int g2 = g1 + 256;             // chunk1 col
    const bool v1 = (g1 >= 0) && (g1 < WW);
    const bool v2 = (l < 20) && (g2 >= 0) && (g2 < WW);

    // vertical sliding sums [field][chunk][k]: 0=I 1=p 2=Ip 3=II
    float s[4][2][4];
    #pragma unroll
    for (int f = 0; f < 4; ++f)
        #pragma unroll
        for (int ch = 0; ch < 2; ++ch)
            #pragma unroll
            for (int k = 0; k < 4; ++k) s[f][ch][k] = 0.f;

    auto load2 = [&](const float* src, int y, float* r) {
        const float* row = src + plane + (size_t)y * WW;
        float4 A = v1 ? *(const float4*)(row + g1) : make_float4(0.f,0.f,0.f,0.f);
        float4 B = v2 ? *(const float4*)(row + g2) : make_float4(0.f,0.f,0.f,0.f);
        r[0]=A.x; r[1]=A.y; r[2]=A.z; r[3]=A.w;
        r[4]=B.x; r[5]=B.y; r[6]=B.z; r[7]=B.w;
    };
    auto acc = [&](const float* ri, const float* rp, float sg) {
        #pragma unroll
        for (int j = 0; j < 8; ++j) {
            const int ch = j >> 2, k = j & 3;
            s[0][ch][k] += sg * ri[j];
            s[1][ch][k] += sg * rp[j];
            s[2][ch][k] += sg * ri[j] * rp[j];
            s[3][ch][k] += sg * ri[j] * ri[j];
        }
    };

    // prime rows [y0-RAD, y0+RAD)
    int yp0 = y0 - RAD; if (yp0 < 0) yp0 = 0;
    int yp1 = y0 + RAD; if (yp1 > HH) yp1 = HH;
    for (int y = yp0; y < yp1; ++y) {
        float ri[8], rp[8];
        load2(I, y, ri); load2(p, y, rp);
        acc(ri, rp, 1.f);
    }

    float pi[8], pp[8];
    if (y0 + RAD < HH) { load2(I, y0 + RAD, pi); load2(p, y0 + RAD, pp); }

    for (int y = y0; y < y0 + SEGF; ++y) {
        if (y + RAD < HH) acc(pi, pp, 1.f);
        // prefetch next add-row and this row's sub-row
        float ni[8], np[8], si[8], sp[8];
        const int yn = y + 1 + RAD;
        const bool nh = (yn < HH) && (y + 1 < y0 + SEGF);
        if (nh) { load2(I, yn, ni); load2(p, yn, np); }
        const int ys = y - RAD;
        if (ys >= 0) { load2(I, ys, si); load2(p, ys, sp); }

        // chained scans (chunk0 then chunk1), prefix -> LDS
        float incl0[4][4];
        #pragma unroll
        for (int f = 0; f < 4; ++f) {
            float c0 = s[f][0][0];
            float c1 = c0 + s[f][0][1];
            float c2 = c1 + s[f][0][2];
            float c3 = c2 + s[f][0][3];
            float t = wscan64(c3, l);
            float tot0 = __shfl(t, 63);
            float b0 = t - c3;
            float d0 = s[f][1][0];
            float d1 = d0 + s[f][1][1];
            float d2 = d1 + s[f][1][2];
            float d3 = d2 + s[f][1][3];
            float u = wscan64(d3, l);
            float b1 = tot0 + (u - d3);
            incl0[f][0] = b0 + c0; incl0[f][1] = b0 + c1;
            incl0[f][2] = b0 + c2; incl0[f][3] = b0 + c3;
            ((float4*)PF[f])[l]      = make_float4(incl0[f][0], incl0[f][1], incl0[f][2], incl0[f][3]);
            ((float4*)PF[f])[64 + l] = make_float4(b1 + d0, b1 + d1, b1 + d2, b1 + d3);
        }
        __syncthreads();   // single-wave workgroup: compiler fence, ~free

        int cv_hi = y + RAD + 1; if (cv_hi > HH) cv_hi = HH;
        int cv_lo = y - RAD;     if (cv_lo < 0)  cv_lo = 0;
        const float cntV = (float)(cv_hi - cv_lo);

        float4 hi0 = ((const float4*)PF[0])[l + 20];
        float4 hi1 = ((const float4*)PF[1])[l + 20];
        float4 hi2 = ((const float4*)PF[2])[l + 20];
        float4 hi3 = ((const float4*)PF[3])[l + 20];
        const float* h0 = (const float*)&hi0;
        const float* h1 = (const float*)&hi1;
        const float* h2 = (const float*)&hi2;
        const float* h3 = (const float*)&hi3;

        unsigned int outw[4];
        #pragma unroll
        for (int k = 0; k < 4; ++k) {
            const int go = x0 + 4 * l + k;
            float bI  = h0[k] - (incl0[0][k] - s[0][0][k]);
            float bp  = h1[k] - (incl0[1][k] - s[1][0][k]);
            float bIp = h2[k] - (incl0[2][k] - s[2][0][k]);
            float bII = h3[k] - (incl0[3][k] - s[3][0][k]);
            int hlo = go - RAD;     if (hlo < 0)  hlo = 0;
            int hhi = go + RAD + 1; if (hhi > WW) hhi = WW;
            const float ic = 1.f / (cntV * (float)(hhi - hlo));
            float mI = bI*ic, mp = bp*ic, mIp = bIp*ic, mII = bII*ic;
            float cov = mIp - mI * mp;
            float var = mII - mI * mI;
            float aa = cov / (var + 1e-3f);
            float bb = mp - aa * mI;
            __half2 h = __float22half2_rn(make_float2(aa, bb));
            outw[k] = *reinterpret_cast<unsigned int*>(&h);
        }
        ((uint4*)(ab + plane + (size_t)y * WW))[(x0 >> 2) + l] =
            make_uint4(outw[0], outw[1], outw[2], outw[3]);

        if (ys >= 0) acc(si, sp, -1.f);
        if (nh) {
            #pragma unroll
            for (int j = 0; j < 8; ++j) { pi[j] = ni[j]; pp[j] = np[j]; }
        }
        __syncthreads();   // protect next iter's PF writes vs this iter's reads
    }
}

// ---------------------------------------------------------------------------
// K_B: same structure on packed a,b; epilogue out = mean_a * I + mean_b
// ---------------------------------------------------------------------------
__global__ __launch_bounds__(64, 3)
void fused_out_kernel(const unsigned int* __restrict__ ab, const float* __restrict__ I,
                      float* __restrict__ out) {
    __shared__ __align__(16) float PF[2][512];
    const int l = threadIdx.x;
    const int bid = blockIdx.x;
    const int strip = bid & 63;
    const int xt = (bid >> 6) & 3;
    const int c = bid >> 8;
    const int x0 = xt * TX;
    const int y0 = strip * SEGF;
    const size_t plane = (size_t)c * (HH * WW);

    const int g1 = x0 - RAD + 4 * l;
    const int g2 = g1 + 256;
    const bool v1 = (g1 >= 0) && (g1 < WW);
    const bool v2 = (l < 20) && (g2 >= 0) && (g2 < WW);

    float s[2][2][4];
    #pragma unroll
    for (int f = 0; f < 2; ++f)
        #pragma unroll
        for (int ch = 0; ch < 2; ++ch)
            #pragma unroll
            for (int k = 0; k < 4; ++k) s[f][ch][k] = 0.f;

    auto load2u = [&](int y, float* ra, float* rb) {
        const unsigned int* row = ab + plane + (size_t)y * WW;
        uint4 A = v1 ? *(const uint4*)(row + g1) : make_uint4(0u,0u,0u,0u);
        uint4 B = v2 ? *(const uint4*)(row + g2) : make_uint4(0u,0u,0u,0u);
        const unsigned int* aw = (const unsigned int*)&A;
        const unsigned int* bw = (const unsigned int*)&B;
        #pragma unroll
        for (int k = 0; k < 4; ++k) {
            __half2 ha = *reinterpret_cast<const __half2*>(&aw[k]);
            float2 fa = __half22float2(ha);
            ra[k] = fa.x; rb[k] = fa.y;
            __half2 hb = *reinterpret_cast<const __half2*>(&bw[k]);
            float2 fb = __half22float2(hb);
            ra[4+k] = fb.x; rb[4+k] = fb.y;
        }
    };
    auto acc = [&](const float* ra, const float* rb, float sg) {
        #pragma unroll
        for (int j = 0; j < 8; ++j) {
            const int ch = j >> 2, k = j & 3;
            s[0][ch][k] += sg * ra[j];
            s[1][ch][k] += sg * rb[j];
        }
    };

    int yp0 = y0 - RAD; if (yp0 < 0) yp0 = 0;
    int yp1 = y0 + RAD; if (yp1 > HH) yp1 = HH;
    for (int y = yp0; y < yp1; ++y) {
        float ra[8], rb[8];
        load2u(y, ra, rb);
        acc(ra, rb, 1.f);
    }

    float pa[8], pb[8];
    if (y0 + RAD < HH) load2u(y0 + RAD, pa, pb);

    for (int y = y0; y < y0 + SEGF; ++y) {
        if (y + RAD < HH) acc(pa, pb, 1.f);
        float na[8], nb[8], sa[8], sb[8];
        const int yn = y + 1 + RAD;
        const bool nh = (yn < HH) && (y + 1 < y0 + SEGF);
        if (nh) load2u(yn, na, nb);
        const int ys = y - RAD;
        if (ys >= 0) load2u(ys, sa, sb);

        float incl0[2][4];
        #pragma unroll
        for (int f = 0; f < 2; ++f) {
            float c0 = s[f][0][0];
            float c1 = c0 + s[f][0][1];
            float c2 = c1 + s[f][0][2];
            float c3 = c2 + s[f][0][3];
            float t = wscan64(c3, l);
            float tot0 = __shfl(t, 63);
            float b0 = t - c3;
            float d0 = s[f][1][0];
            float d1 = d0 + s[f][1][1];
            float d2 = d1 + s[f][1][2];
            float d3 = d2 + s[f][1][3];
            float u = wscan64(d3, l);
            float b1 = tot0 + (u - d3);
            incl0[f][0] = b0 + c0; incl0[f][1] = b0 + c1;
            incl0[f][2] = b0 + c2; incl0[f][3] = b0 + c3;
            ((float4*)PF[f])[l]      = make_float4(incl0[f][0], incl0[f][1], incl0[f][2], incl0[f][3]);
            ((float4*)PF[f])[64 + l] = make_float4(b1 + d0, b1 + d1, b1 + d2, b1 + d3);
        }
        __syncthreads();

        int cv_hi = y + RAD + 1; if (cv_hi > HH) cv_hi = HH;
        int cv_lo = y - RAD;     if (cv_lo < 0)  cv_lo = 0;
        const float cntV = (float)(cv_hi - cv_lo);

        float4 hiA = ((const float4*)PF[0])[l + 20];
        float4 hiB = ((const float4*)PF[1])[l + 20];
        const float* hA = (const float*)&hiA;
        const float* hB = (const float*)&hiB;
        float4 Iv = ((const float4*)(I + plane + (size_t)y * WW))[(x0 >> 2) + l];
        const float* Ik = (const float*)&Iv;

        float oo[4];
        #pragma unroll
        for (int k = 0; k < 4; ++k) {
            const int go = x0 + 4 * l + k;
            float ba = hA[k] - (incl0[0][k] - s[0][0][k]);
            float bb = hB[k] - (incl0[1][k] - s[1][0][k]);
            int hlo = go - RAD;     if (hlo < 0)  hlo = 0;
            int hhi = go + RAD + 1; if (hhi > WW) hhi = WW;
            const float ic = 1.f / (cntV * (float)(hhi - hlo));
            oo[k] = (ba * ic) * Ik[k] + bb * ic;
        }
        ((float4*)(out + plane + (size_t)y * WW))[(x0 >> 2) + l] =
            make_float4(oo[0], oo[1], oo[2], oo[3]);

        if (ys >= 0) acc(sa, sb, -1.f);
        if (nh) {
            #pragma unroll
            for (int j = 0; j < 8; ++j) { pa[j] = na[j]; pb[j] = nb[j]; }
        }
        __syncthreads();
    }
}

extern "C" void kernel_launch(void* const* d_in, const int* in_sizes, int n_in,
                              void* d_out, int out_size, void* d_ws, size_t ws_size,
                              hipStream_t stream) {
    const float* I = (const float*)d_in[0];
    const float* p = (const float*)d_in[1];
    float* out = (float*)d_out;

    const int N = in_sizes[0];           // B*C*H*W
    const int BC = N / (HH * WW);

    unsigned int* ab = (unsigned int*)d_ws;   // fp16x2 {a,b} per pixel

    const int nblk = BC * (WW / TX) * (HH / SEGF);   // BC * 4 * 64
    fused_ab_kernel<<<dim3(nblk), 64, 0, stream>>>(I, p, ab);
    fused_out_kernel<<<dim3(nblk), 64, 0, stream>>>(ab, I, out);
}